// Round 10
// baseline (232.202 us; speedup 1.0000x reference)
//
#include <hip/hip_runtime.h>

// Problem constants
#define LL    262144
#define GG    8
#define JJ    8
#define FGF   16
#define WW    31
#define PAD1  15
#define CHUNK 256                   // positions per wave-chunk
#define CPW   2                     // chunks per wave
#define WAVES 4
#define NTHR  (WAVES * 64)          // 256
#define SPAN  (WAVES * CPW * CHUNK) // 2048 positions per block
#define NBX   (LL / SPAN)           // 128 x-blocks
#define SLOTS 288                   // staged slots per chunk: halo 15 + 256 + 16

typedef __bf16 bf16x8 __attribute__((ext_vector_type(8)));
typedef float  f32x4  __attribute__((ext_vector_type(4)));

__device__ inline unsigned short f2bf(float f) {
    unsigned int u = __float_as_uint(f);
    u = (u + 0x7FFF + ((u >> 16) & 1)) >> 16;   // RNE
    return (unsigned short)u;
}

// Y[16,L] = P[16,256]·XW[256,L] per group (K = 31w x 8j padded to 256).
// A = X-fragment, B = P-fragment (swapped) -> D: col=lane&15 (filter),
// row=q*4+reg (position) -> f32x4 coalesced stores.
//
// ROUND-10 STRUCTURE: ZERO main-loop barriers. Each wave owns a private
// 288-slot LDS slice and stages/computes its chunks independently; all
// ordering is per-wave vmcnt/lgkmcnt. Rationale (R0-R9 evidence): every
// phased variant stalled at 85-110us with ~30% occupancy because each
// per-tile __syncthreads (vmcnt(0) drain) coupled all waves to the slowest
// wave's staging loads. Private slices make stalls private; 16 waves/CU of
// TLP hide them.
//
// Session laws:
//  - >=7 waves/EU launch bound => 64-VGPR class => catastrophic spill
//    (R2,R5). Working set b[32]+F[32] needs 128-class: LB(256,4).
//    Spill tripwire: FETCH_SIZE >> 60 MB.
//  - transpose-in-thread staging, consecutive-lane b128 LDS writes:
//    0 bank conflicts (R3-R9 measured).
//  - d_ws triggers ~160us/iter harness re-poison fills (R8) - never use.
__global__ __launch_bounds__(NTHR, 4)
void conv_mfma(const float* __restrict__ x, const float* __restrict__ p,
               const int* __restrict__ rel, float* __restrict__ out)
{
    __shared__ unsigned short pw[32 * 16 * 8];        // [w][f][j] bf16 (8 KB)
    __shared__ unsigned short xs[WAVES][SLOTS * 8];   // private slices (18 KB)

    const int t = threadIdx.x;
    const int g = blockIdx.y;

    // Relation rows (uniform -> scalar regs).
    const long r0 = rel[g * JJ + 0], r1 = rel[g * JJ + 1];
    const long r2 = rel[g * JJ + 2], r3 = rel[g * JJ + 3];
    const long r4 = rel[g * JJ + 4], r5 = rel[g * JJ + 5];
    const long r6 = rel[g * JJ + 6], r7 = rel[g * JJ + 7];

    // ---- stage P cooperatively: linear LDS writes, L2-hot scattered reads.
    {
        const float* pg = p + (long)g * FGF * JJ * WW;
        #pragma unroll
        for (int k = 0; k < 16; ++k) {
            int i = t + k * NTHR;            // i = (w*16 + f)*8 + j
            int w = i >> 7;
            int f = (i >> 3) & 15;
            int j = i & 7;
            float v = (w < WW) ? pg[(f * JJ + j) * WW + w] : 0.0f;
            pw[i] = f2bf(v);
        }
    }
    __syncthreads();                         // the ONLY unconditional barrier

    const int lane = t & 63;
    const int wid  = t >> 6;
    const int col  = lane & 15;
    const int q    = lane >> 4;

    bf16x8 b[8];                             // P frags: b[s] = P[f=col, j=*, w=s*4+q]
    #pragma unroll
    for (int s = 0; s < 8; ++s)
        b[s] = *(const bf16x8*)&pw[((s * 4 + q) * 16 + col) * 8];

    unsigned short* xsl = &xs[wid][0];       // this wave's private slice
    const int pb = col + q + 1;              // lane's base slot
    #define LDS8(pos) (*(const bf16x8*)&xsl[(pos) * 8])

    // ---- per-wave independent chunk loop (no inter-wave sync)
    #pragma unroll
    for (int c = 0; c < CPW; ++c) {
        const long W0 = (long)blockIdx.x * SPAN + (wid * CPW + c) * CHUNK;

        // stage slice: slot pp <-> global W0 - 16 + pp, pp in [0, SLOTS).
        // 8 coalesced row loads per slot, one b128 LDS write (conflict-free).
        #pragma unroll
        for (int pn = 0; pn < 5; ++pn) {
            int pp = pn * 64 + lane;
            if (pp < SLOTS) {
                long gp = W0 - 16 + pp;
                uint4 pk;
                if (gp >= 0 && gp < LL) {
                    float v0 = x[r0 * LL + gp], v1 = x[r1 * LL + gp];
                    float v2 = x[r2 * LL + gp], v3 = x[r3 * LL + gp];
                    float v4 = x[r4 * LL + gp], v5 = x[r5 * LL + gp];
                    float v6 = x[r6 * LL + gp], v7 = x[r7 * LL + gp];
                    pk.x = (unsigned)f2bf(v0) | ((unsigned)f2bf(v1) << 16);
                    pk.y = (unsigned)f2bf(v2) | ((unsigned)f2bf(v3) << 16);
                    pk.z = (unsigned)f2bf(v4) | ((unsigned)f2bf(v5) << 16);
                    pk.w = (unsigned)f2bf(v6) | ((unsigned)f2bf(v7) << 16);
                } else {
                    pk.x = pk.y = pk.z = pk.w = 0u;   // outside [0, L)
                }
                *(uint4*)&xsl[pp * 8] = pk;
            }
        }
        // per-wave lgkmcnt ordering suffices: only this wave reads xsl.

        // compute 16 output tiles; rolling window frag(T,s+4)==frag(T+1,s)
        bf16x8 F0a = LDS8(pb + 0), F0b = LDS8(pb + 4),
               F0c = LDS8(pb + 8), F0d = LDS8(pb + 12);
        #pragma unroll
        for (int T = 0; T < 16; ++T) {
            const int o = pb + T * 16 + 16;
            bf16x8 F1a = LDS8(o + 0), F1b = LDS8(o + 4),
                   F1c = LDS8(o + 8), F1d = LDS8(o + 12);

            f32x4 acc = {0.f, 0.f, 0.f, 0.f};
            acc = __builtin_amdgcn_mfma_f32_16x16x32_bf16(F0a, b[0], acc, 0, 0, 0);
            acc = __builtin_amdgcn_mfma_f32_16x16x32_bf16(F0b, b[1], acc, 0, 0, 0);
            acc = __builtin_amdgcn_mfma_f32_16x16x32_bf16(F0c, b[2], acc, 0, 0, 0);
            acc = __builtin_amdgcn_mfma_f32_16x16x32_bf16(F0d, b[3], acc, 0, 0, 0);
            acc = __builtin_amdgcn_mfma_f32_16x16x32_bf16(F1a, b[4], acc, 0, 0, 0);
            acc = __builtin_amdgcn_mfma_f32_16x16x32_bf16(F1b, b[5], acc, 0, 0, 0);
            acc = __builtin_amdgcn_mfma_f32_16x16x32_bf16(F1c, b[6], acc, 0, 0, 0);
            acc = __builtin_amdgcn_mfma_f32_16x16x32_bf16(F1d, b[7], acc, 0, 0, 0);

            // lane holds positions (W0 + T*16 + q*4 .. +3) of filter `col`
            const long kc0 = W0 + (long)T * 16 + q * 4;
            const size_t ro = (size_t)(g * FGF + col) * LL;
            *(f32x4*)&out[ro + kc0] = acc;

            F0a = F1a; F0b = F1b; F0c = F1c; F0d = F1d;   // roll window
        }
        // next chunk overwrites xsl; per-wave DS ordering makes this safe.
    }
    #undef LDS8

    // ---- merged edge fix. Reference TRUNCATES the window at data edges:
    // overwrite first/last 15 columns in exact fp32. Needs ordering after
    // the owning wave's main stores -> conditional barrier (block-uniform).
    if (blockIdx.x == 0 || blockIdx.x == NBX - 1) {
        __syncthreads();   // drains all waves' stores (vmcnt(0) before barrier)
        const int f  = t >> 4;
        const int qq = t & 15;
        if (qq < PAD1) {
            const bool left = (blockIdx.x == 0);
            float a = 0.0f;
            for (int j = 0; j < JJ; ++j) {
                const float* pf = p + (((long)(g * FGF + f)) * JJ + j) * WW;
                const float* xj = x + (long)rel[g * JJ + j] * LL + (left ? 0 : LL - WW);
                #pragma unroll
                for (int w = 0; w < WW; ++w) {
                    // left:  y[qq]      = sum_{w <= qq+15} x[w]      * K[w]
                    // right: y[L-15+qq] = sum_{w >= qq+1 } x[L-31+w] * K[w]
                    bool use = left ? (w <= qq + PAD1) : (w >= qq + 1);
                    if (use) a += xj[w] * pf[w];
                }
            }
            const size_t ro = (size_t)(g * FGF + f) * LL;
            out[ro + (left ? (long)qq : (long)(LL - PAD1) + qq)] = a;
        }
    }
}

extern "C" void kernel_launch(void* const* d_in, const int* in_sizes, int n_in,
                              void* d_out, int out_size, void* d_ws, size_t ws_size,
                              hipStream_t stream)
{
    const float* x   = (const float*)d_in[0];
    const float* p   = (const float*)d_in[1];
    const int*   rel = (const int*)d_in[2];
    float* out = (float*)d_out;

    dim3 grid(NBX, GG);   // (128, 8) = 1024 blocks = exactly 4/CU, one round
    conv_mfma<<<grid, NTHR, 0, stream>>>(x, p, rel, out);
}

// Round 11
// 214.487 us; speedup vs baseline: 1.0826x; 1.0826x over previous
//
#include <hip/hip_runtime.h>

// Problem constants
#define LL    262144
#define GG    8
#define JJ    8
#define FGF   16
#define WW    31
#define PAD1  15
#define CHUNK 256                   // positions per wave-chunk
#define CPW   2                     // chunks per wave
#define WAVES 4
#define NTHR  (WAVES * 64)          // 256
#define SPAN  (WAVES * CPW * CHUNK) // 2048 positions per block
#define NBX   (LL / SPAN)           // 128 x-blocks
#define SLOTS 288                   // staged slots per chunk: halo 15 + 256 + 16 + 1
#define PADX  130                   // xo row stride (floats), breaks bank alias

typedef __bf16 bf16x8 __attribute__((ext_vector_type(8)));
typedef float  f32x4  __attribute__((ext_vector_type(4)));

__device__ inline unsigned short f2bf(float f) {
    unsigned int u = __float_as_uint(f);
    u = (u + 0x7FFF + ((u >> 16) & 1)) >> 16;   // RNE
    return (unsigned short)u;
}

// Y[16,L] = P[16,256]·XW[256,L] per group (K = 31w x 8j padded to 256).
// A = X-frag, B = P-frag (swapped) -> D: col=lane&15 (filter), row=q*4+reg
// (position).
//
// ROUND-11 THEORY: the session-wide 85-110us plateau is OUTPUT-WRITE DRAM
// row thrash. Direct stores scatter 16 rows x 64B at 1MB stride per instr
// (~1.6 TB/s effective; 134MB -> ~84us = the plateau). Evidence: R8's
// fillBuffer hits 6.5 TB/s at 9.6%% occupancy (pattern >> parallelism);
// compute/traffic floors are ~8/27us. FIX: accumulate 16x128-pos f32 tile
// in LDS per wave, flush as 512B-contiguous stores (2KB runs per row/wave).
// Secondary: hoist all 40 staging loads (clamped addr) before packing = MLP.
//
// Session laws:
//  - >=7 waves/EU launch bound => 64-VGPR class => catastrophic spill
//    (R2,R5). LB(256,4) -> 128 cap. Spill tripwire: FETCH >> 60 MB.
//  - transpose-in-thread staging, consecutive-lane b128 writes: 0 conflicts.
//  - d_ws triggers ~160us/iter harness re-poison fills (R8) - never use.
//  - per-tile __syncthreads NOT the bottleneck (R10 falsified).
__global__ __launch_bounds__(NTHR, 4)
void conv_mfma(const float* __restrict__ x, const float* __restrict__ p,
               const int* __restrict__ rel, float* __restrict__ out)
{
    __shared__ unsigned short pw[32 * 16 * 8];        // [w][f][j] bf16 (8 KB)
    __shared__ unsigned short xs[WAVES][SLOTS * 8];   // x slices (18 KB)
    __shared__ float xo[WAVES][16 * PADX];            // out-transpose (32.5 KB)

    const int t = threadIdx.x;
    const int g = blockIdx.y;

    const long r0 = rel[g * JJ + 0], r1 = rel[g * JJ + 1];
    const long r2 = rel[g * JJ + 2], r3 = rel[g * JJ + 3];
    const long r4 = rel[g * JJ + 4], r5 = rel[g * JJ + 5];
    const long r6 = rel[g * JJ + 6], r7 = rel[g * JJ + 7];

    // ---- stage P cooperatively: linear LDS writes, L2-hot scattered reads.
    {
        const float* pg = p + (long)g * FGF * JJ * WW;
        #pragma unroll
        for (int k = 0; k < 16; ++k) {
            int i = t + k * NTHR;            // i = (w*16 + f)*8 + j
            int w = i >> 7;
            int f = (i >> 3) & 15;
            int j = i & 7;
            float v = (w < WW) ? pg[(f * JJ + j) * WW + w] : 0.0f;
            pw[i] = f2bf(v);
        }
    }
    __syncthreads();                         // the only unconditional barrier

    const int lane = t & 63;
    const int wid  = t >> 6;
    const int col  = lane & 15;
    const int q    = lane >> 4;

    bf16x8 b[8];                             // P frags: b[s] = P[f=col, j=*, w=s*4+q]
    #pragma unroll
    for (int s = 0; s < 8; ++s)
        b[s] = *(const bf16x8*)&pw[((s * 4 + q) * 16 + col) * 8];

    unsigned short* xsl = &xs[wid][0];       // wave-private slices
    float*          xol = &xo[wid][0];
    const int pb = col + q + 1;              // lane's base slot
    #define LDS8(pos) (*(const bf16x8*)&xsl[(pos) * 8])

    // ---- per-wave independent chunk loop (no inter-wave sync)
    #pragma unroll
    for (int c = 0; c < CPW; ++c) {
        const long W0 = (long)blockIdx.x * SPAN + (wid * CPW + c) * CHUNK;

        // stage slice, two phases for MLP: (1) issue all 40 loads with
        // clamped addresses (uniform control flow), (2) mask+pack+ds_write.
        float v[5][8];
        #pragma unroll
        for (int pn = 0; pn < 5; ++pn) {
            int  pp = pn * 64 + lane;
            long gp = W0 - 16 + pp;
            long gc = (gp >= 0 && gp < LL && pp < SLOTS) ? gp : 0;
            v[pn][0] = x[r0 * LL + gc]; v[pn][1] = x[r1 * LL + gc];
            v[pn][2] = x[r2 * LL + gc]; v[pn][3] = x[r3 * LL + gc];
            v[pn][4] = x[r4 * LL + gc]; v[pn][5] = x[r5 * LL + gc];
            v[pn][6] = x[r6 * LL + gc]; v[pn][7] = x[r7 * LL + gc];
        }
        #pragma unroll
        for (int pn = 0; pn < 5; ++pn) {
            int  pp = pn * 64 + lane;
            long gp = W0 - 16 + pp;
            bool ok = (gp >= 0 && gp < LL);
            if (pp < SLOTS) {
                uint4 pk;
                pk.x = ok ? ((unsigned)f2bf(v[pn][0]) | ((unsigned)f2bf(v[pn][1]) << 16)) : 0u;
                pk.y = ok ? ((unsigned)f2bf(v[pn][2]) | ((unsigned)f2bf(v[pn][3]) << 16)) : 0u;
                pk.z = ok ? ((unsigned)f2bf(v[pn][4]) | ((unsigned)f2bf(v[pn][5]) << 16)) : 0u;
                pk.w = ok ? ((unsigned)f2bf(v[pn][6]) | ((unsigned)f2bf(v[pn][7]) << 16)) : 0u;
                *(uint4*)&xsl[pp * 8] = pk;
            }
        }

        // compute 16 tiles; rolling window frag(T,s+4)==frag(T+1,s).
        // acc -> LDS transpose buffer; flush every 8 tiles as contiguous
        // 512B-per-row stores (the DRAM-friendly write path).
        bf16x8 F0a = LDS8(pb + 0), F0b = LDS8(pb + 4),
               F0c = LDS8(pb + 8), F0d = LDS8(pb + 12);
        #pragma unroll
        for (int T = 0; T < 16; ++T) {
            const int o = pb + T * 16 + 16;
            bf16x8 F1a = LDS8(o + 0), F1b = LDS8(o + 4),
                   F1c = LDS8(o + 8), F1d = LDS8(o + 12);

            f32x4 acc = {0.f, 0.f, 0.f, 0.f};
            acc = __builtin_amdgcn_mfma_f32_16x16x32_bf16(F0a, b[0], acc, 0, 0, 0);
            acc = __builtin_amdgcn_mfma_f32_16x16x32_bf16(F0b, b[1], acc, 0, 0, 0);
            acc = __builtin_amdgcn_mfma_f32_16x16x32_bf16(F0c, b[2], acc, 0, 0, 0);
            acc = __builtin_amdgcn_mfma_f32_16x16x32_bf16(F0d, b[3], acc, 0, 0, 0);
            acc = __builtin_amdgcn_mfma_f32_16x16x32_bf16(F1a, b[4], acc, 0, 0, 0);
            acc = __builtin_amdgcn_mfma_f32_16x16x32_bf16(F1b, b[5], acc, 0, 0, 0);
            acc = __builtin_amdgcn_mfma_f32_16x16x32_bf16(F1c, b[6], acc, 0, 0, 0);
            acc = __builtin_amdgcn_mfma_f32_16x16x32_bf16(F1d, b[7], acc, 0, 0, 0);

            // lane holds positions (T*16 + q*4 .. +3) of filter `col`
            *(f32x4*)&xol[col * PADX + (T & 7) * 16 + q * 4] = acc;

            if ((T & 7) == 7) {              // flush 128 positions x 16 rows
                const long fp0 = W0 + (long)(T >> 3) * 128;
                #pragma unroll
                for (int f = 0; f < 16; ++f) {
                    float2 vv = *(const float2*)&xol[f * PADX + lane * 2];
                    *(float2*)&out[(size_t)(g * FGF + f) * LL + fp0 + lane * 2] = vv;
                }
            }

            F0a = F1a; F0b = F1b; F0c = F1c; F0d = F1d;   // roll window
        }
        // next chunk overwrites xsl/xol; per-wave DS ordering makes it safe.
    }
    #undef LDS8

    // ---- merged edge fix. Reference TRUNCATES the window at data edges:
    // overwrite first/last 15 columns in exact fp32.
    if (blockIdx.x == 0 || blockIdx.x == NBX - 1) {
        __syncthreads();   // all waves' flushes drained (vmcnt(0) pre-barrier)
        const int f  = t >> 4;
        const int qq = t & 15;
        if (qq < PAD1) {
            const bool left = (blockIdx.x == 0);
            float a = 0.0f;
            for (int j = 0; j < JJ; ++j) {
                const float* pf = p + (((long)(g * FGF + f)) * JJ + j) * WW;
                const float* xj = x + (long)rel[g * JJ + j] * LL + (left ? 0 : LL - WW);
                #pragma unroll
                for (int w = 0; w < WW; ++w) {
                    // left:  y[qq]      = sum_{w <= qq+15} x[w]      * K[w]
                    // right: y[L-15+qq] = sum_{w >= qq+1 } x[L-31+w] * K[w]
                    bool use = left ? (w <= qq + PAD1) : (w >= qq + 1);
                    if (use) a += xj[w] * pf[w];
                }
            }
            const size_t ro = (size_t)(g * FGF + f) * LL;
            out[ro + (left ? (long)qq : (long)(LL - PAD1) + qq)] = a;
        }
    }
}

extern "C" void kernel_launch(void* const* d_in, const int* in_sizes, int n_in,
                              void* d_out, int out_size, void* d_ws, size_t ws_size,
                              hipStream_t stream)
{
    const float* x   = (const float*)d_in[0];
    const float* p   = (const float*)d_in[1];
    const int*   rel = (const int*)d_in[2];
    float* out = (float*)d_out;

    dim3 grid(NBX, GG);   // (128, 8) = 1024 blocks
    conv_mfma<<<grid, NTHR, 0, stream>>>(x, p, rel, out);
}